// Round 13
// baseline (213.295 us; speedup 1.0000x reference)
//
#include <hip/hip_runtime.h>

// Problem constants (from reference)
#define NMOV 250000
#define NTRM 8000
#define NTOT 318000          // NMOV + 8000 terminals + 60000 fillers
#define GNX 512
#define GNY 512
#define GNZ 8

// ---------- shared helpers ----------
static __device__ __forceinline__ float axis_ov(float p0, float s, int k) {
    float lo = (float)k;
    return fmaxf(fminf(p0 + s, lo + 1.0f) - fmaxf(p0, lo), 0.0f);
}
static __device__ __forceinline__ float ovz(float pz, float pzh, int k) {
    float lo = (float)k;
    return fmaxf(fminf(pzh, lo + 1.0f) - fmaxf(pz, lo), 0.0f);
}
// Clamped box for node i (identical math everywhere -> identical tile ranges)
static __device__ __forceinline__ void node_box(
    int i, const float* __restrict__ pos,
    const float* __restrict__ nsx, const float* __restrict__ nsy, const float* __restrict__ nsz,
    float& px, float& py, float& pz, float& ex, float& ey, float& ez, float& w)
{
    px = pos[i]; py = pos[NTOT + i]; pz = pos[2 * NTOT + i];
    float sx = nsx[i], sy = nsy[i], sz = nsz[i];
    const float S2 = 1.4142135623730951f;
    bool terminal = (i >= NMOV) && (i < NMOV + NTRM);
    if (!terminal) {
        float cx = fmaxf(sx, S2), cy = fmaxf(sy, S2), cz = fmaxf(sz, S2);
        px += (sx - cx) * 0.5f;
        py += (sy - cy) * 0.5f;
        pz += (sz - cz) * 0.5f;
        w = (sx * sy * sz) / (cx * cy * cz);
        ex = cx; ey = cy; ez = cz;
    } else {
        ex = sx; ey = sy; ez = sz; w = 1.0f;
    }
}

// =====================================================================
// MAIN PATH: 8x8 tiles, sharded 64B inline-payload buckets (fill),
// then ONE WAVE PER TILE consuming slots via the SCALAR pipe (accum):
// all slot addresses are blockIdx-uniform -> s_load into SGPRs ->
// VALU reads SGPR operands directly. No LDS at all (r12 analysis:
// uniform ds_read_b128 broadcast was LDS-issue-bound, ~26us/CU).
// slot (64B line): [pxl,pxh,pyl,pyh][w*oz0..3][w*oz4..7][pad]
// =====================================================================
#define NTIL8 4096           // 64x64 tiles
#define NSH8 8               // counter shards per tile
#define CAPS8 40             // per (tile,shard); E~13.4, +7 sigma

__global__ void fill8s_kernel(const float* __restrict__ pos,
                              const float* __restrict__ nsx,
                              const float* __restrict__ nsy,
                              const float* __restrict__ nsz,
                              int* __restrict__ counts,
                              float4* __restrict__ bucket,
                              float* __restrict__ out) {
    int i = blockIdx.x * blockDim.x + threadIdx.x;
    if (i == 0) { out[0] = 0.0f; out[1] = 0.0f; }   // ordered before accum by kernel boundary
    if (i >= NTOT) return;

    float pxl, pyl, pzl, ex, ey, ez, w;
    node_box(i, pos, nsx, nsy, nsz, pxl, pyl, pzl, ex, ey, ez, w);
    float pxh = pxl + ex, pyh = pyl + ey, pzh = pzl + ez;

    float4 q = make_float4(pxl, pxh, pyl, pyh);
    float4 a = make_float4(w * ovz(pzl, pzh, 0), w * ovz(pzl, pzh, 1),
                           w * ovz(pzl, pzh, 2), w * ovz(pzl, pzh, 3));
    float4 b = make_float4(w * ovz(pzl, pzh, 4), w * ovz(pzl, pzh, 5),
                           w * ovz(pzl, pzh, 6), w * ovz(pzl, pzh, 7));
    float4 pad = make_float4(0.0f, 0.0f, 0.0f, 0.0f);

    int ix0 = max((int)floorf(pxl), 0);
    int ix1 = min((int)floorf(pxh), GNX - 1);
    int iy0 = max((int)floorf(pyl), 0);
    int iy1 = min((int)floorf(pyh), GNY - 1);
    int tx0 = ix0 >> 3, tx1 = ix1 >> 3;
    int ty0 = iy0 >> 3, ty1 = iy1 >> 3;
    int s = i & (NSH8 - 1);

    for (int tx = tx0; tx <= tx1; ++tx) {
        for (int ty = ty0; ty <= ty1; ++ty) {
            int cell = (((tx << 6) + ty) << 3) + s;     // (tile*8 + shard)
            int idx = atomicAdd(&counts[cell], 1);
            if (idx < CAPS8) {
                float4* sp = bucket + ((size_t)(cell * CAPS8 + idx) << 2);
                sp[0] = q; sp[1] = a; sp[2] = b; sp[3] = pad;  // full 64B line
            }
        }
    }
}

// One 64-thread block (= one wave) per tile. lane = one (x,y) column,
// 8 z-bins in registers. Slot reads are blockIdx-uniform over a
// const-restrict region -> scalar loads (SGPR); VALU uses them directly.
__launch_bounds__(64)
__global__ void accum1w_kernel(const int* __restrict__ counts,
                               const float4* __restrict__ bucket,
                               float* __restrict__ out) {
    int t = blockIdx.x;                 // uniform per block/wave
    int lane = threadIdx.x;             // 0..63
    int tx = t >> 6, ty = t & 63;
    int x = (tx << 3) + (lane >> 3);
    int y = (ty << 3) + (lane & 7);
    float Xf = (float)x, Yf = (float)y;
    float X1 = Xf + 1.0f, Y1 = Yf + 1.0f;

    float acc[GNZ];
    #pragma unroll
    for (int z = 0; z < GNZ; ++z) acc[z] = 0.0f;

    int cbase = t << 3;
    for (int s = 0; s < NSH8; ++s) {
        int n = min(counts[cbase + s], CAPS8);                  // uniform
        const float4* sp = bucket + ((size_t)((cbase + s) * CAPS8) << 2);
        #pragma unroll 2
        for (int j = 0; j < n; ++j) {
            float4 q = sp[(j << 2) + 0];   // uniform addr -> s_load
            float4 a = sp[(j << 2) + 1];
            float4 b = sp[(j << 2) + 2];
            float ox = fmaxf(fminf(q.y, X1) - fmaxf(q.x, Xf), 0.0f);
            float oy = fmaxf(fminf(q.w, Y1) - fmaxf(q.z, Yf), 0.0f);
            float oxy = ox * oy;
            acc[0] = fmaf(oxy, a.x, acc[0]);
            acc[1] = fmaf(oxy, a.y, acc[1]);
            acc[2] = fmaf(oxy, a.z, acc[2]);
            acc[3] = fmaf(oxy, a.w, acc[3]);
            acc[4] = fmaf(oxy, b.x, acc[4]);
            acc[5] = fmaf(oxy, b.y, acc[5]);
            acc[6] = fmaf(oxy, b.z, acc[6]);
            acc[7] = fmaf(oxy, b.w, acc[7]);
        }
    }

    // column-local cost/max (interior only), wave shuffle reduce, 1 atomic/wave
    float cost = 0.0f;
    float mx = 1.0f;   // border bins forced to TD*BIN_VOL = 1.0
    if (x >= 1 && x <= GNX - 2 && y >= 1 && y <= GNY - 2) {
        #pragma unroll
        for (int z = 1; z <= GNZ - 2; ++z) {
            cost += fmaxf(acc[z] - 1.0f, 0.0f);
            mx = fmaxf(mx, acc[z]);
        }
    }
    #pragma unroll
    for (int off = 32; off >= 1; off >>= 1) {
        cost += __shfl_down(cost, off);
        mx = fmaxf(mx, __shfl_down(mx, off));
    }
    if (lane == 0) {
        atomicAdd(&out[0], cost);                       // non-returning: pipelines
        atomicMax((int*)&out[1], __float_as_int(mx));   // all values >= 0
    }
}

// =====================================================================
// FALLBACK (r8/r10 proven path, verbatim): unsharded 8x8 buckets + LDS accum.
// =====================================================================
#define CAP8 176

__global__ void fill8_kernel(const float* __restrict__ pos,
                             const float* __restrict__ nsx,
                             const float* __restrict__ nsy,
                             const float* __restrict__ nsz,
                             int* __restrict__ counts,
                             float4* __restrict__ bucket,
                             float* __restrict__ out) {
    int i = blockIdx.x * blockDim.x + threadIdx.x;
    if (i == 0) { out[0] = 0.0f; out[1] = 0.0f; }
    if (i >= NTOT) return;
    float pxl, pyl, pzl, ex, ey, ez, w;
    node_box(i, pos, nsx, nsy, nsz, pxl, pyl, pzl, ex, ey, ez, w);
    float pxh = pxl + ex, pyh = pyl + ey, pzh = pzl + ez;
    float4 q = make_float4(pxl, pxh, pyl, pyh);
    float4 a = make_float4(w * ovz(pzl, pzh, 0), w * ovz(pzl, pzh, 1),
                           w * ovz(pzl, pzh, 2), w * ovz(pzl, pzh, 3));
    float4 b = make_float4(w * ovz(pzl, pzh, 4), w * ovz(pzl, pzh, 5),
                           w * ovz(pzl, pzh, 6), w * ovz(pzl, pzh, 7));
    float4 pad = make_float4(0.0f, 0.0f, 0.0f, 0.0f);
    int ix0 = max((int)floorf(pxl), 0);
    int ix1 = min((int)floorf(pxh), GNX - 1);
    int iy0 = max((int)floorf(pyl), 0);
    int iy1 = min((int)floorf(pyh), GNY - 1);
    int tx0 = ix0 >> 3, tx1 = ix1 >> 3;
    int ty0 = iy0 >> 3, ty1 = iy1 >> 3;
    for (int tx = tx0; tx <= tx1; ++tx) {
        for (int ty = ty0; ty <= ty1; ++ty) {
            int cell = (tx << 6) + ty;
            int idx = atomicAdd(&counts[cell], 1);
            if (idx < CAP8) {
                float4* sp = bucket + ((size_t)(cell * CAP8 + idx) << 2);
                sp[0] = q; sp[1] = a; sp[2] = b; sp[3] = pad;
            }
        }
    }
}

__launch_bounds__(256)
__global__ void accum8_kernel(const int* __restrict__ counts,
                              const float4* __restrict__ bucket,
                              float* __restrict__ out) {
    __shared__ float4 seg[4][CAP8 * 3];
    __shared__ float scost[4], smx[4];
    int wid = threadIdx.x >> 6;
    int lane = threadIdx.x & 63;
    int t = (blockIdx.x << 2) + wid;
    int tx = t >> 6, ty = t & 63;
    int x = (tx << 3) + (lane >> 3);
    int y = (ty << 3) + (lane & 7);
    float Xf = (float)x, Yf = (float)y;
    float acc[GNZ];
    #pragma unroll
    for (int z = 0; z < GNZ; ++z) acc[z] = 0.0f;
    int n = min(counts[t], CAP8);
    const float4* slot = bucket + ((size_t)t * CAP8 << 2);
    for (int e = lane; e < n; e += 64) {
        const float4* sp = slot + (e << 2);
        seg[wid][e * 3 + 0] = sp[0];
        seg[wid][e * 3 + 1] = sp[1];
        seg[wid][e * 3 + 2] = sp[2];
    }
    for (int j = 0; j < n; ++j) {
        float4 q = seg[wid][3 * j];
        float ox = fmaxf(fminf(q.y, Xf + 1.0f) - fmaxf(q.x, Xf), 0.0f);
        float oy = fmaxf(fminf(q.w, Yf + 1.0f) - fmaxf(q.z, Yf), 0.0f);
        float oxy = ox * oy;
        float4 a = seg[wid][3 * j + 1];
        float4 b = seg[wid][3 * j + 2];
        acc[0] = fmaf(oxy, a.x, acc[0]);
        acc[1] = fmaf(oxy, a.y, acc[1]);
        acc[2] = fmaf(oxy, a.z, acc[2]);
        acc[3] = fmaf(oxy, a.w, acc[3]);
        acc[4] = fmaf(oxy, b.x, acc[4]);
        acc[5] = fmaf(oxy, b.y, acc[5]);
        acc[6] = fmaf(oxy, b.z, acc[6]);
        acc[7] = fmaf(oxy, b.w, acc[7]);
    }
    float cost = 0.0f;
    float mx = 1.0f;
    if (x >= 1 && x <= GNX - 2 && y >= 1 && y <= GNY - 2) {
        #pragma unroll
        for (int z = 1; z <= GNZ - 2; ++z) {
            cost += fmaxf(acc[z] - 1.0f, 0.0f);
            mx = fmaxf(mx, acc[z]);
        }
    }
    #pragma unroll
    for (int off = 32; off >= 1; off >>= 1) {
        cost += __shfl_down(cost, off);
        mx = fmaxf(mx, __shfl_down(mx, off));
    }
    if (lane == 0) { scost[wid] = cost; smx[wid] = mx; }
    __syncthreads();
    if (threadIdx.x == 0) {
        float c = scost[0] + scost[1] + scost[2] + scost[3];
        float m = fmaxf(fmaxf(smx[0], smx[1]), fmaxf(smx[2], smx[3]));
        atomicAdd(&out[0], c);
        atomicMax((int*)&out[1], __float_as_int(m));
    }
}

extern "C" void kernel_launch(void* const* d_in, const int* in_sizes, int n_in,
                              void* d_out, int out_size, void* d_ws, size_t ws_size,
                              hipStream_t stream) {
    const float* pos = (const float*)d_in[0];
    const float* nsx = (const float*)d_in[1];
    const float* nsy = (const float*)d_in[2];
    const float* nsz = (const float*)d_in[3];
    float* out = (float*)d_out;

    // Sharded path: counts 32768 ints (128KB), bucket at 128KB, ~80MB slots
    const size_t CNT_S = (size_t)NTIL8 * NSH8 * sizeof(int);           // 131072
    const size_t NEED_S = CNT_S + (size_t)NTIL8 * NSH8 * CAPS8 * 64;   // ~80.1 MB
    // Fallback (r8): counts 16KB@0, bucket @64KB, ~46.2 MB
    const size_t NEED_F = 65536 + (size_t)NTIL8 * CAP8 * 64;

    if (ws_size >= NEED_S) {
        int* counts = (int*)d_ws;
        float4* bucket = (float4*)((char*)d_ws + CNT_S);
        hipMemsetAsync(counts, 0, CNT_S, stream);
        fill8s_kernel<<<(NTOT + 255) / 256, 256, 0, stream>>>(
            pos, nsx, nsy, nsz, counts, bucket, out);
        accum1w_kernel<<<NTIL8, 64, 0, stream>>>(counts, bucket, out);
    } else if (ws_size >= NEED_F) {
        int* counts = (int*)d_ws;
        float4* bucket = (float4*)((char*)d_ws + 65536);
        hipMemsetAsync(counts, 0, NTIL8 * sizeof(int), stream);
        fill8_kernel<<<(NTOT + 255) / 256, 256, 0, stream>>>(
            pos, nsx, nsy, nsz, counts, bucket, out);
        accum8_kernel<<<NTIL8 / 4, 256, 0, stream>>>(counts, bucket, out);
    }
    // (observed ws_size = 256 MiB; smaller fallbacks unnecessary)
}

// Round 14
// 137.889 us; speedup vs baseline: 1.5469x; 1.5469x over previous
//
#include <hip/hip_runtime.h>

// Problem constants (from reference)
#define NMOV 250000
#define NTRM 8000
#define NTOT 318000          // NMOV + 8000 terminals + 60000 fillers
#define GNX 512
#define GNY 512
#define GNZ 8

// ---------- shared helpers ----------
static __device__ __forceinline__ float ovz(float pz, float pzh, int k) {
    float lo = (float)k;
    return fmaxf(fminf(pzh, lo + 1.0f) - fmaxf(pz, lo), 0.0f);
}
// Clamped box for node i (identical math everywhere -> identical tile ranges)
static __device__ __forceinline__ void node_box(
    int i, const float* __restrict__ pos,
    const float* __restrict__ nsx, const float* __restrict__ nsy, const float* __restrict__ nsz,
    float& px, float& py, float& pz, float& ex, float& ey, float& ez, float& w)
{
    px = pos[i]; py = pos[NTOT + i]; pz = pos[2 * NTOT + i];
    float sx = nsx[i], sy = nsy[i], sz = nsz[i];
    const float S2 = 1.4142135623730951f;
    bool terminal = (i >= NMOV) && (i < NMOV + NTRM);
    if (!terminal) {
        float cx = fmaxf(sx, S2), cy = fmaxf(sy, S2), cz = fmaxf(sz, S2);
        px += (sx - cx) * 0.5f;
        py += (sy - cy) * 0.5f;
        pz += (sz - cz) * 0.5f;
        w = (sx * sy * sz) / (cx * cy * cz);
        ex = cx; ey = cy; ez = cz;
    } else {
        ex = sx; ey = sy; ez = sz; w = 1.0f;
    }
}

// =====================================================================
// MAIN PATH: 8x8 tiles, sharded counters, 32B inline-payload slots.
// slot: [pxl,pxh,pyl,pyh][w*oz(iz0), w*oz(iz0+1), w*oz(iz0+2), iz0bits]
// (z-box spans <=3 bins; skipped z's contributed exactly 0.0 before,
// so arithmetic is bit-identical to the proven 64B-slot path.)
// r13 lesson: accum slot reads must be VECTOR loads + LDS broadcast;
// scalar-pipe s_load chains are latency-serial (122us disaster).
// =====================================================================
#define NTIL8 4096           // 64x64 tiles
#define NSH8 8               // counter shards per tile (r12: -11.5us vs unsharded)
#define CAPS8 40             // per (tile,shard); E~13.4, +7 sigma
#define TOTCAP 160           // staged slots per tile; E~107, +5 sigma

__global__ void fill32_kernel(const float* __restrict__ pos,
                              const float* __restrict__ nsx,
                              const float* __restrict__ nsy,
                              const float* __restrict__ nsz,
                              int* __restrict__ counts,
                              float4* __restrict__ bucket,
                              float* __restrict__ out) {
    int i = blockIdx.x * blockDim.x + threadIdx.x;
    if (i == 0) { out[0] = 0.0f; out[1] = 0.0f; }   // ordered before accum by kernel boundary
    if (i >= NTOT) return;

    float pxl, pyl, pzl, ex, ey, ez, w;
    node_box(i, pos, nsx, nsy, nsz, pxl, pyl, pzl, ex, ey, ez, w);
    float pxh = pxl + ex, pyh = pyl + ey, pzh = pzl + ez;

    int iz0 = max((int)floorf(pzl), 0);              // <= 6 (pzl < 7)
    float wza = w * ovz(pzl, pzh, iz0);
    float wzb = w * ovz(pzl, pzh, iz0 + 1);          // iz0+1 <= 7 always
    float wzc = (iz0 + 2 <= GNZ - 1) ? w * ovz(pzl, pzh, iz0 + 2) : 0.0f;

    float4 s0 = make_float4(pxl, pxh, pyl, pyh);
    float4 s1 = make_float4(wza, wzb, wzc, __int_as_float(iz0));

    int ix0 = max((int)floorf(pxl), 0);
    int ix1 = min((int)floorf(pxh), GNX - 1);
    int iy0 = max((int)floorf(pyl), 0);
    int iy1 = min((int)floorf(pyh), GNY - 1);
    int tx0 = ix0 >> 3, tx1 = ix1 >> 3;
    int ty0 = iy0 >> 3, ty1 = iy1 >> 3;
    int s = i & (NSH8 - 1);

    for (int tx = tx0; tx <= tx1; ++tx) {
        for (int ty = ty0; ty <= ty1; ++ty) {
            int cell = (((tx << 6) + ty) << 3) + s;     // tile*8 + shard
            int idx = atomicAdd(&counts[cell], 1);
            if (idx < CAPS8) {
                float4* sp = bucket + ((size_t)(cell * CAPS8 + idx) << 1);
                sp[0] = s0; sp[1] = s1;                 // 32B slot
            }
        }
    }
}

// 4 waves per block, one 8x8 tile per wave (lane = (x,y) column, 8 z in regs).
// Flattened staging into split segQ/segR (conflict-free b128), LDS broadcast
// inner loop, readfirstlane-scalarized switch on iz0 -> 3 static-index FMAs.
__launch_bounds__(256)
__global__ void accum32_kernel(const int* __restrict__ counts,
                               const float4* __restrict__ bucket,
                               float* __restrict__ out) {
    __shared__ float4 segQ[4][TOTCAP];
    __shared__ float4 segR[4][TOTCAP];
    __shared__ float scost[4], smx[4];

    int wid = threadIdx.x >> 6;
    int lane = threadIdx.x & 63;
    int t = (blockIdx.x << 2) + wid;
    int tx = t >> 6, ty = t & 63;
    int x = (tx << 3) + (lane >> 3);
    int y = (ty << 3) + (lane & 7);
    float Xf = (float)x, Yf = (float)y;
    float X1 = Xf + 1.0f, Y1 = Yf + 1.0f;

    float acc[GNZ];
    #pragma unroll
    for (int z = 0; z < GNZ; ++z) acc[z] = 0.0f;

    // per-wave uniform loads of the 8 shard counts -> prefix in registers
    int cbase = t << 3;
    int c0 = min(counts[cbase + 0], CAPS8);
    int c1 = min(counts[cbase + 1], CAPS8);
    int c2 = min(counts[cbase + 2], CAPS8);
    int c3 = min(counts[cbase + 3], CAPS8);
    int c4 = min(counts[cbase + 4], CAPS8);
    int c5 = min(counts[cbase + 5], CAPS8);
    int c6 = min(counts[cbase + 6], CAPS8);
    int c7 = min(counts[cbase + 7], CAPS8);
    int o1 = c0, o2 = o1 + c1, o3 = o2 + c2, o4 = o3 + c3;
    int o5 = o4 + c4, o6 = o5 + c5, o7 = o6 + c6;
    int tot = o7 + c7;
    if (tot > TOTCAP) tot = TOTCAP;

    for (int g = lane; g < tot; g += 64) {
        int s = (g >= o1) + (g >= o2) + (g >= o3) + (g >= o4) +
                (g >= o5) + (g >= o6) + (g >= o7);
        int off = 0;
        off = (g >= o1) ? o1 : off;
        off = (g >= o2) ? o2 : off;
        off = (g >= o3) ? o3 : off;
        off = (g >= o4) ? o4 : off;
        off = (g >= o5) ? o5 : off;
        off = (g >= o6) ? o6 : off;
        off = (g >= o7) ? o7 : off;
        int idx = g - off;
        const float4* sp = bucket + ((size_t)((cbase + s) * CAPS8 + idx) << 1);
        segQ[wid][g] = sp[0];
        segR[wid][g] = sp[1];
    }
    // wave-private LDS write->read: compiler inserts lgkmcnt waits; no barrier.

    for (int j = 0; j < tot; ++j) {
        float4 q = segQ[wid][j];           // same-address broadcast: conflict-free
        float4 r = segR[wid][j];
        float ox = fmaxf(fminf(q.y, X1) - fmaxf(q.x, Xf), 0.0f);
        float oy = fmaxf(fminf(q.w, Y1) - fmaxf(q.z, Yf), 0.0f);
        float oxy = ox * oy;
        int iz0 = __builtin_amdgcn_readfirstlane(__float_as_int(r.w));  // uniform
        switch (iz0) {
        case 0: acc[0]=fmaf(oxy,r.x,acc[0]); acc[1]=fmaf(oxy,r.y,acc[1]); acc[2]=fmaf(oxy,r.z,acc[2]); break;
        case 1: acc[1]=fmaf(oxy,r.x,acc[1]); acc[2]=fmaf(oxy,r.y,acc[2]); acc[3]=fmaf(oxy,r.z,acc[3]); break;
        case 2: acc[2]=fmaf(oxy,r.x,acc[2]); acc[3]=fmaf(oxy,r.y,acc[3]); acc[4]=fmaf(oxy,r.z,acc[4]); break;
        case 3: acc[3]=fmaf(oxy,r.x,acc[3]); acc[4]=fmaf(oxy,r.y,acc[4]); acc[5]=fmaf(oxy,r.z,acc[5]); break;
        case 4: acc[4]=fmaf(oxy,r.x,acc[4]); acc[5]=fmaf(oxy,r.y,acc[5]); acc[6]=fmaf(oxy,r.z,acc[6]); break;
        case 5: acc[5]=fmaf(oxy,r.x,acc[5]); acc[6]=fmaf(oxy,r.y,acc[6]); acc[7]=fmaf(oxy,r.z,acc[7]); break;
        default: acc[6]=fmaf(oxy,r.x,acc[6]); acc[7]=fmaf(oxy,r.y,acc[7]); break;  // iz0==6, wzc==0
        }
    }

    // column-local cost/max (interior only), then wave + block reduce
    float cost = 0.0f;
    float mx = 1.0f;   // border bins forced to TD*BIN_VOL = 1.0
    if (x >= 1 && x <= GNX - 2 && y >= 1 && y <= GNY - 2) {
        #pragma unroll
        for (int z = 1; z <= GNZ - 2; ++z) {
            cost += fmaxf(acc[z] - 1.0f, 0.0f);
            mx = fmaxf(mx, acc[z]);
        }
    }
    #pragma unroll
    for (int off = 32; off >= 1; off >>= 1) {
        cost += __shfl_down(cost, off);
        mx = fmaxf(mx, __shfl_down(mx, off));
    }
    if (lane == 0) { scost[wid] = cost; smx[wid] = mx; }
    __syncthreads();
    if (threadIdx.x == 0) {
        float c = scost[0] + scost[1] + scost[2] + scost[3];
        float m = fmaxf(fmaxf(smx[0], smx[1]), fmaxf(smx[2], smx[3]));
        atomicAdd(&out[0], c);
        atomicMax((int*)&out[1], __float_as_int(m));   // all values >= 0
    }
}

// =====================================================================
// FALLBACK (r12 proven, verbatim): sharded 64B slots + LDS accum.
// =====================================================================
__global__ void fill8s_kernel(const float* __restrict__ pos,
                              const float* __restrict__ nsx,
                              const float* __restrict__ nsy,
                              const float* __restrict__ nsz,
                              int* __restrict__ counts,
                              float4* __restrict__ bucket,
                              float* __restrict__ out) {
    int i = blockIdx.x * blockDim.x + threadIdx.x;
    if (i == 0) { out[0] = 0.0f; out[1] = 0.0f; }
    if (i >= NTOT) return;
    float pxl, pyl, pzl, ex, ey, ez, w;
    node_box(i, pos, nsx, nsy, nsz, pxl, pyl, pzl, ex, ey, ez, w);
    float pxh = pxl + ex, pyh = pyl + ey, pzh = pzl + ez;
    float4 q = make_float4(pxl, pxh, pyl, pyh);
    float4 a = make_float4(w * ovz(pzl, pzh, 0), w * ovz(pzl, pzh, 1),
                           w * ovz(pzl, pzh, 2), w * ovz(pzl, pzh, 3));
    float4 b = make_float4(w * ovz(pzl, pzh, 4), w * ovz(pzl, pzh, 5),
                           w * ovz(pzl, pzh, 6), w * ovz(pzl, pzh, 7));
    float4 pad = make_float4(0.0f, 0.0f, 0.0f, 0.0f);
    int ix0 = max((int)floorf(pxl), 0);
    int ix1 = min((int)floorf(pxh), GNX - 1);
    int iy0 = max((int)floorf(pyl), 0);
    int iy1 = min((int)floorf(pyh), GNY - 1);
    int tx0 = ix0 >> 3, tx1 = ix1 >> 3;
    int ty0 = iy0 >> 3, ty1 = iy1 >> 3;
    int s = i & (NSH8 - 1);
    for (int tx = tx0; tx <= tx1; ++tx) {
        for (int ty = ty0; ty <= ty1; ++ty) {
            int cell = (((tx << 6) + ty) << 3) + s;
            int idx = atomicAdd(&counts[cell], 1);
            if (idx < CAPS8) {
                float4* sp = bucket + ((size_t)(cell * CAPS8 + idx) << 2);
                sp[0] = q; sp[1] = a; sp[2] = b; sp[3] = pad;
            }
        }
    }
}

__launch_bounds__(256)
__global__ void accum8s_kernel(const int* __restrict__ counts,
                               const float4* __restrict__ bucket,
                               float* __restrict__ out) {
    __shared__ float4 seg[4][TOTCAP * 3];
    __shared__ float scost[4], smx[4];
    int wid = threadIdx.x >> 6;
    int lane = threadIdx.x & 63;
    int t = (blockIdx.x << 2) + wid;
    int tx = t >> 6, ty = t & 63;
    int x = (tx << 3) + (lane >> 3);
    int y = (ty << 3) + (lane & 7);
    float Xf = (float)x, Yf = (float)y;
    float acc[GNZ];
    #pragma unroll
    for (int z = 0; z < GNZ; ++z) acc[z] = 0.0f;
    int cbase = t << 3;
    int c0 = min(counts[cbase + 0], CAPS8);
    int c1 = min(counts[cbase + 1], CAPS8);
    int c2 = min(counts[cbase + 2], CAPS8);
    int c3 = min(counts[cbase + 3], CAPS8);
    int c4 = min(counts[cbase + 4], CAPS8);
    int c5 = min(counts[cbase + 5], CAPS8);
    int c6 = min(counts[cbase + 6], CAPS8);
    int c7 = min(counts[cbase + 7], CAPS8);
    int o1 = c0, o2 = o1 + c1, o3 = o2 + c2, o4 = o3 + c3;
    int o5 = o4 + c4, o6 = o5 + c5, o7 = o6 + c6;
    int tot = o7 + c7;
    if (tot > TOTCAP) tot = TOTCAP;
    for (int g = lane; g < tot; g += 64) {
        int s = (g >= o1) + (g >= o2) + (g >= o3) + (g >= o4) +
                (g >= o5) + (g >= o6) + (g >= o7);
        int off = 0;
        off = (g >= o1) ? o1 : off;
        off = (g >= o2) ? o2 : off;
        off = (g >= o3) ? o3 : off;
        off = (g >= o4) ? o4 : off;
        off = (g >= o5) ? o5 : off;
        off = (g >= o6) ? o6 : off;
        off = (g >= o7) ? o7 : off;
        int idx = g - off;
        const float4* sp = bucket + ((size_t)((cbase + s) * CAPS8 + idx) << 2);
        seg[wid][g * 3 + 0] = sp[0];
        seg[wid][g * 3 + 1] = sp[1];
        seg[wid][g * 3 + 2] = sp[2];
    }
    for (int j = 0; j < tot; ++j) {
        float4 q = seg[wid][3 * j];
        float ox = fmaxf(fminf(q.y, Xf + 1.0f) - fmaxf(q.x, Xf), 0.0f);
        float oy = fmaxf(fminf(q.w, Yf + 1.0f) - fmaxf(q.z, Yf), 0.0f);
        float oxy = ox * oy;
        float4 a = seg[wid][3 * j + 1];
        float4 b = seg[wid][3 * j + 2];
        acc[0] = fmaf(oxy, a.x, acc[0]);
        acc[1] = fmaf(oxy, a.y, acc[1]);
        acc[2] = fmaf(oxy, a.z, acc[2]);
        acc[3] = fmaf(oxy, a.w, acc[3]);
        acc[4] = fmaf(oxy, b.x, acc[4]);
        acc[5] = fmaf(oxy, b.y, acc[5]);
        acc[6] = fmaf(oxy, b.z, acc[6]);
        acc[7] = fmaf(oxy, b.w, acc[7]);
    }
    float cost = 0.0f;
    float mx = 1.0f;
    if (x >= 1 && x <= GNX - 2 && y >= 1 && y <= GNY - 2) {
        #pragma unroll
        for (int z = 1; z <= GNZ - 2; ++z) {
            cost += fmaxf(acc[z] - 1.0f, 0.0f);
            mx = fmaxf(mx, acc[z]);
        }
    }
    #pragma unroll
    for (int off = 32; off >= 1; off >>= 1) {
        cost += __shfl_down(cost, off);
        mx = fmaxf(mx, __shfl_down(mx, off));
    }
    if (lane == 0) { scost[wid] = cost; smx[wid] = mx; }
    __syncthreads();
    if (threadIdx.x == 0) {
        float c = scost[0] + scost[1] + scost[2] + scost[3];
        float m = fmaxf(fmaxf(smx[0], smx[1]), fmaxf(smx[2], smx[3]));
        atomicAdd(&out[0], c);
        atomicMax((int*)&out[1], __float_as_int(m));
    }
}

extern "C" void kernel_launch(void* const* d_in, const int* in_sizes, int n_in,
                              void* d_out, int out_size, void* d_ws, size_t ws_size,
                              hipStream_t stream) {
    const float* pos = (const float*)d_in[0];
    const float* nsx = (const float*)d_in[1];
    const float* nsy = (const float*)d_in[2];
    const float* nsz = (const float*)d_in[3];
    float* out = (float*)d_out;

    const size_t CNT = (size_t)NTIL8 * NSH8 * sizeof(int);              // 128 KB
    const size_t NEED32 = CNT + (size_t)NTIL8 * NSH8 * CAPS8 * 32;      // ~42.1 MB
    const size_t NEED64 = CNT + (size_t)NTIL8 * NSH8 * CAPS8 * 64;      // ~80.1 MB

    if (ws_size >= NEED32) {
        int* counts = (int*)d_ws;
        float4* bucket = (float4*)((char*)d_ws + CNT);
        hipMemsetAsync(counts, 0, CNT, stream);
        fill32_kernel<<<(NTOT + 255) / 256, 256, 0, stream>>>(
            pos, nsx, nsy, nsz, counts, bucket, out);
        accum32_kernel<<<NTIL8 / 4, 256, 0, stream>>>(counts, bucket, out);
    } else if (ws_size >= NEED64) {
        int* counts = (int*)d_ws;
        float4* bucket = (float4*)((char*)d_ws + CNT);
        hipMemsetAsync(counts, 0, CNT, stream);
        fill8s_kernel<<<(NTOT + 255) / 256, 256, 0, stream>>>(
            pos, nsx, nsy, nsz, counts, bucket, out);
        accum8s_kernel<<<NTIL8 / 4, 256, 0, stream>>>(counts, bucket, out);
    }
}